// Round 1
// baseline (471.487 us; speedup 1.0000x reference)
//
#include <hip/hip_runtime.h>
#include <math.h>

#define W 4
#define NUM_HEADS 32
#define HEAD_SIZE 128
#define G 8            // kv heads
#define QPG 4          // query heads per kv head
#define BLOCK_SZ 16
#define NUM_BLOCKS 1024
#define MAX_BLOCKS 32
#define S 32           // num seqs
#define SCALE 0.08838834764831845f  // 1/sqrt(128)

// Kernel 1 (and fused fallback). Each block handles one (w,s,g) [or (s,g) with
// an internal loop over w when FUSED]. 256 threads = 8 half-wave accumulators,
// each an independent online softmax over tokens strided by 8. Lane l of a
// half-wave owns dims [4l, 4l+4) -> float4 coalesced K/V row loads.
template <bool FUSED>
__global__ __launch_bounds__(256)
void pa_partial_kernel(const float* __restrict__ query,
                       const float* __restrict__ key_cache,
                       const float* __restrict__ value_cache,
                       const int* __restrict__ block_tables,
                       const int* __restrict__ context_lens,
                       float* __restrict__ acc_ws,
                       float* __restrict__ m_ws,
                       float* __restrict__ e_ws,
                       float* __restrict__ out)
{
    const int bx = blockIdx.x;
    int s, g, w0, w1;
    if (FUSED) {            // bx = s*G + g
        s = bx / G; g = bx % G; w0 = 0; w1 = W;
    } else {                // bx = (w*S + s)*G + g
        g = bx % G;
        int t = bx / G;
        s = t % S;
        w0 = t / S; w1 = w0 + 1;
    }
    const int tid   = threadIdx.x;
    const int accid = tid >> 5;     // 0..7  (half-wave accumulator id)
    const int lane  = tid & 31;     // lane within half-wave
    const int d0    = lane * 4;     // 4 dims owned by this lane

    __shared__ int   bt_lds[MAX_BLOCKS];
    __shared__ float sm_m[8][QPG];
    __shared__ float sm_e[8][QPG];
    __shared__ float sm_acc[8][QPG][HEAD_SIZE];

    // q fragments: 4 query heads x 4 dims per lane
    float4 qf[QPG];
#pragma unroll
    for (int qi = 0; qi < QPG; ++qi)
        qf[qi] = *reinterpret_cast<const float4*>(
            query + ((size_t)s * NUM_HEADS + g * QPG + qi) * HEAD_SIZE + d0);

    float  m_i[QPG], e_i[QPG];
    float4 acc[QPG];
#pragma unroll
    for (int qi = 0; qi < QPG; ++qi) {
        m_i[qi] = -INFINITY; e_i[qi] = 0.f;
        acc[qi] = make_float4(0.f, 0.f, 0.f, 0.f);
    }

    const size_t stride_blk = (size_t)G * BLOCK_SZ * HEAD_SIZE;  // elems per paged block

    for (int w = w0; w < w1; ++w) {
        __syncthreads();   // protect bt_lds reuse across w iterations
        if (tid < MAX_BLOCKS)
            bt_lds[tid] = block_tables[((size_t)w * S + s) * MAX_BLOCKS + tid];
        __syncthreads();

        const int ctx = context_lens[w * S + s];
        const float* kbase = key_cache   + ((size_t)w * NUM_BLOCKS * G + g) * BLOCK_SZ * HEAD_SIZE;
        const float* vbase = value_cache + ((size_t)w * NUM_BLOCKS * G + g) * BLOCK_SZ * HEAD_SIZE;

        for (int t = accid; t < ctx; t += 8) {
            const int blk  = bt_lds[t >> 4];
            const int slot = t & (BLOCK_SZ - 1);
            const size_t off = (size_t)blk * stride_blk + (size_t)slot * HEAD_SIZE + d0;
            const float4 kx = *reinterpret_cast<const float4*>(kbase + off);
            const float4 vx = *reinterpret_cast<const float4*>(vbase + off);

            // partial dots for the 4 query heads
            float4 dv;
            dv.x = qf[0].x * kx.x + qf[0].y * kx.y + qf[0].z * kx.z + qf[0].w * kx.w;
            dv.y = qf[1].x * kx.x + qf[1].y * kx.y + qf[1].z * kx.z + qf[1].w * kx.w;
            dv.z = qf[2].x * kx.x + qf[2].y * kx.y + qf[2].z * kx.z + qf[2].w * kx.w;
            dv.w = qf[3].x * kx.x + qf[3].y * kx.y + qf[3].z * kx.z + qf[3].w * kx.w;
            // reduce within the 32-lane half (xor masks < 32 stay in-half)
#pragma unroll
            for (int o = 16; o > 0; o >>= 1) {
                dv.x += __shfl_xor(dv.x, o);
                dv.y += __shfl_xor(dv.y, o);
                dv.z += __shfl_xor(dv.z, o);
                dv.w += __shfl_xor(dv.w, o);
            }
            const float lg[QPG] = {dv.x * SCALE, dv.y * SCALE, dv.z * SCALE, dv.w * SCALE};
#pragma unroll
            for (int qi = 0; qi < QPG; ++qi) {
                const float mn    = fmaxf(m_i[qi], lg[qi]);
                const float alpha = __expf(m_i[qi] - mn);
                const float p     = __expf(lg[qi] - mn);
                m_i[qi] = mn;
                e_i[qi] = e_i[qi] * alpha + p;
                acc[qi].x = acc[qi].x * alpha + p * vx.x;
                acc[qi].y = acc[qi].y * alpha + p * vx.y;
                acc[qi].z = acc[qi].z * alpha + p * vx.z;
                acc[qi].w = acc[qi].w * alpha + p * vx.w;
            }
        }
    }

    // merge the 8 accumulators through LDS
#pragma unroll
    for (int qi = 0; qi < QPG; ++qi) {
        if (lane == 0) { sm_m[accid][qi] = m_i[qi]; sm_e[accid][qi] = e_i[qi]; }
        sm_acc[accid][qi][d0 + 0] = acc[qi].x;
        sm_acc[accid][qi][d0 + 1] = acc[qi].y;
        sm_acc[accid][qi][d0 + 2] = acc[qi].z;
        sm_acc[accid][qi][d0 + 3] = acc[qi].w;
    }
    __syncthreads();

    for (int p = tid; p < QPG * HEAD_SIZE; p += 256) {
        const int qi = p >> 7;
        const int d  = p & (HEAD_SIZE - 1);
        float gm = -INFINITY;
#pragma unroll
        for (int h = 0; h < 8; ++h) gm = fmaxf(gm, sm_m[h][qi]);
        float num = 0.f, den = 0.f;
#pragma unroll
        for (int h = 0; h < 8; ++h) {
            const float sc = __expf(sm_m[h][qi] - gm);
            num += sm_acc[h][qi][d] * sc;
            den += sm_e[h][qi] * sc;
        }
        if (FUSED) {
            out[((size_t)s * NUM_HEADS + g * QPG + qi) * HEAD_SIZE + d] = num / den;
        } else {
            const size_t idx = (((size_t)w0 * S + s) * G + g) * QPG + qi;
            acc_ws[idx * HEAD_SIZE + d] = num;
            if (d == 0) { m_ws[idx] = gm; e_ws[idx] = den; }
        }
    }
}

// Kernel 2: cross-rank log-sum-exp combine. One block per (s,g).
__global__ __launch_bounds__(256)
void pa_reduce_kernel(const float* __restrict__ acc_ws,
                      const float* __restrict__ m_ws,
                      const float* __restrict__ e_ws,
                      float* __restrict__ out)
{
    const int bx = blockIdx.x;       // s*G + g
    const int s = bx / G, g = bx % G;
    const int tid = threadIdx.x;
    for (int p = tid; p < QPG * HEAD_SIZE; p += 256) {
        const int qi = p >> 7;
        const int d  = p & (HEAD_SIZE - 1);
        float mw[W], ew[W];
        float gm = -INFINITY;
#pragma unroll
        for (int w = 0; w < W; ++w) {
            const size_t idx = (((size_t)w * S + s) * G + g) * QPG + qi;
            mw[w] = m_ws[idx];
            ew[w] = e_ws[idx];
            gm = fmaxf(gm, mw[w]);
        }
        float num = 0.f, den = 0.f;
#pragma unroll
        for (int w = 0; w < W; ++w) {
            const float sc = __expf(mw[w] - gm);
            const size_t idx = (((size_t)w * S + s) * G + g) * QPG + qi;
            num += acc_ws[idx * HEAD_SIZE + d] * sc;
            den += ew[w] * sc;
        }
        out[((size_t)s * NUM_HEADS + g * QPG + qi) * HEAD_SIZE + d] = num / den;
    }
}

extern "C" void kernel_launch(void* const* d_in, const int* in_sizes, int n_in,
                              void* d_out, int out_size, void* d_ws, size_t ws_size,
                              hipStream_t stream) {
    const float* query       = (const float*)d_in[0];
    const float* key_cache   = (const float*)d_in[1];
    const float* value_cache = (const float*)d_in[2];
    const int*   block_tables = (const int*)d_in[3];
    const int*   context_lens = (const int*)d_in[4];
    float* out = (float*)d_out;

    const size_t n_acc   = (size_t)W * S * G * QPG * HEAD_SIZE;  // 524288
    const size_t n_stats = (size_t)W * S * G * QPG;              // 4096
    const size_t need    = (n_acc + 2 * n_stats) * sizeof(float);

    if (ws_size >= need) {
        float* acc_ws = (float*)d_ws;
        float* m_ws   = acc_ws + n_acc;
        float* e_ws   = m_ws + n_stats;
        pa_partial_kernel<false><<<W * S * G, 256, 0, stream>>>(
            query, key_cache, value_cache, block_tables, context_lens,
            acc_ws, m_ws, e_ws, nullptr);
        pa_reduce_kernel<<<S * G, 256, 0, stream>>>(acc_ws, m_ws, e_ws, out);
    } else {
        pa_partial_kernel<true><<<S * G, 256, 0, stream>>>(
            query, key_cache, value_cache, block_tables, context_lens,
            nullptr, nullptr, nullptr, out);
    }
}

// Round 2
// 463.744 us; speedup vs baseline: 1.0167x; 1.0167x over previous
//
#include <hip/hip_runtime.h>
#include <math.h>

#define W 4
#define NUM_HEADS 32
#define HEAD_SIZE 128
#define G 8            // kv heads
#define QPG 4          // query heads per kv head
#define BLOCK_SZ 16
#define NUM_BLOCKS 1024
#define MAX_BLOCKS 32
#define S 32           // num seqs
#define SPLIT 2        // blocks per (w,s,g)
#define NPART (W * SPLIT)   // partials per (s,g) for the reduce
#define SCALE 0.08838834764831845f  // 1/sqrt(128)
#define NEG_BIG (-1e30f)

// Per-block elems in the paged cache: [block][g][slot][d]
#define BLK_STRIDE (G * BLOCK_SZ * HEAD_SIZE)   // 16384
#define WG_STRIDE  (NUM_BLOCKS * BLK_STRIDE)    // per-w elems (fits int for w*...: use size_t at base)

// Kernel 1: one block per (w,s,g,p). 256 threads = 8 half-wave online-softmax
// accumulators; global half id h = accid + 8*p takes tokens t ≡ h (mod 16),
// unrolled 2 tokens per iteration (t, t+16). Lane l owns dims [4l,4l+4).
// Writes unnormalized acc + (m, esum) per (r=w*SPLIT+p, s, g, qi) partial.
__global__ __launch_bounds__(256, 5)
void pa_partial_kernel(const float* __restrict__ query,
                       const float* __restrict__ key_cache,
                       const float* __restrict__ value_cache,
                       const int* __restrict__ block_tables,
                       const int* __restrict__ context_lens,
                       float* __restrict__ acc_ws,
                       float* __restrict__ m_ws,
                       float* __restrict__ e_ws)
{
    int bx = blockIdx.x;                 // ((w*S + s)*G + g)*SPLIT + p
    const int p = bx % SPLIT; bx /= SPLIT;
    const int g = bx % G;     bx /= G;
    const int s = bx % S;
    const int w = bx / S;

    const int tid   = threadIdx.x;
    const int accid = tid >> 5;          // 0..7
    const int lane  = tid & 31;
    const int d0    = lane * 4;
    const int h     = accid + 8 * p;     // global half id 0..15

    __shared__ int   bt_lds[MAX_BLOCKS];
    __shared__ float sm_m[8][QPG];
    __shared__ float sm_e[8][QPG];
    __shared__ float sm_acc[8][QPG][HEAD_SIZE];

    if (tid < MAX_BLOCKS)
        bt_lds[tid] = block_tables[((size_t)w * S + s) * MAX_BLOCKS + tid];
    __syncthreads();

    float4 qf[QPG];
#pragma unroll
    for (int qi = 0; qi < QPG; ++qi)
        qf[qi] = *reinterpret_cast<const float4*>(
            query + ((size_t)s * NUM_HEADS + g * QPG + qi) * HEAD_SIZE + d0);

    const int ctx = context_lens[w * S + s];
    const float* kbase = key_cache   + (size_t)w * WG_STRIDE + (size_t)g * BLOCK_SZ * HEAD_SIZE;
    const float* vbase = value_cache + (size_t)w * WG_STRIDE + (size_t)g * BLOCK_SZ * HEAD_SIZE;

    float  m_i[QPG], e_i[QPG];
    float4 acc[QPG];
#pragma unroll
    for (int qi = 0; qi < QPG; ++qi) {
        m_i[qi] = NEG_BIG; e_i[qi] = 0.f;
        acc[qi] = make_float4(0.f, 0.f, 0.f, 0.f);
    }

    for (int t = h; t < ctx; t += 2 * 16) {
        // token 1 (always valid: t < ctx)
        const int off1 = bt_lds[t >> 4] * BLK_STRIDE + (t & 15) * HEAD_SIZE + d0;
        const float4 k1 = *reinterpret_cast<const float4*>(kbase + off1);
        const float4 v1 = *reinterpret_cast<const float4*>(vbase + off1);
        // token 2 (maybe past ctx)
        const int  t2   = t + 16;
        const bool vld2 = t2 < ctx;
        float4 k2 = make_float4(0.f, 0.f, 0.f, 0.f);
        float4 v2 = make_float4(0.f, 0.f, 0.f, 0.f);
        if (vld2) {
            const int off2 = bt_lds[t2 >> 4] * BLK_STRIDE + (t2 & 15) * HEAD_SIZE + d0;
            k2 = *reinterpret_cast<const float4*>(kbase + off2);
            v2 = *reinterpret_cast<const float4*>(vbase + off2);
        }

        float4 dv1, dv2;
        dv1.x = qf[0].x*k1.x + qf[0].y*k1.y + qf[0].z*k1.z + qf[0].w*k1.w;
        dv1.y = qf[1].x*k1.x + qf[1].y*k1.y + qf[1].z*k1.z + qf[1].w*k1.w;
        dv1.z = qf[2].x*k1.x + qf[2].y*k1.y + qf[2].z*k1.z + qf[2].w*k1.w;
        dv1.w = qf[3].x*k1.x + qf[3].y*k1.y + qf[3].z*k1.z + qf[3].w*k1.w;
        dv2.x = qf[0].x*k2.x + qf[0].y*k2.y + qf[0].z*k2.z + qf[0].w*k2.w;
        dv2.y = qf[1].x*k2.x + qf[1].y*k2.y + qf[1].z*k2.z + qf[1].w*k2.w;
        dv2.z = qf[2].x*k2.x + qf[2].y*k2.y + qf[2].z*k2.z + qf[2].w*k2.w;
        dv2.w = qf[3].x*k2.x + qf[3].y*k2.y + qf[3].z*k2.z + qf[3].w*k2.w;
#pragma unroll
        for (int o = 16; o > 0; o >>= 1) {      // stays within the 32-lane half
            dv1.x += __shfl_xor(dv1.x, o); dv1.y += __shfl_xor(dv1.y, o);
            dv1.z += __shfl_xor(dv1.z, o); dv1.w += __shfl_xor(dv1.w, o);
            dv2.x += __shfl_xor(dv2.x, o); dv2.y += __shfl_xor(dv2.y, o);
            dv2.z += __shfl_xor(dv2.z, o); dv2.w += __shfl_xor(dv2.w, o);
        }
        const float l1[QPG] = {dv1.x*SCALE, dv1.y*SCALE, dv1.z*SCALE, dv1.w*SCALE};
        float l2[QPG] = {dv2.x*SCALE, dv2.y*SCALE, dv2.z*SCALE, dv2.w*SCALE};
#pragma unroll
        for (int qi = 0; qi < QPG; ++qi) if (!vld2) l2[qi] = NEG_BIG;

#pragma unroll
        for (int qi = 0; qi < QPG; ++qi) {
            const float mn    = fmaxf(m_i[qi], fmaxf(l1[qi], l2[qi]));
            const float alpha = __expf(m_i[qi] - mn);
            const float p1    = __expf(l1[qi] - mn);
            const float p2    = __expf(l2[qi] - mn);
            m_i[qi] = mn;
            e_i[qi] = e_i[qi] * alpha + (p1 + p2);
            acc[qi].x = fmaf(acc[qi].x, alpha, fmaf(p1, v1.x, p2 * v2.x));
            acc[qi].y = fmaf(acc[qi].y, alpha, fmaf(p1, v1.y, p2 * v2.y));
            acc[qi].z = fmaf(acc[qi].z, alpha, fmaf(p1, v1.z, p2 * v2.z));
            acc[qi].w = fmaf(acc[qi].w, alpha, fmaf(p1, v1.w, p2 * v2.w));
        }
    }

    // merge the 8 local half-accumulators through LDS
#pragma unroll
    for (int qi = 0; qi < QPG; ++qi) {
        if (lane == 0) { sm_m[accid][qi] = m_i[qi]; sm_e[accid][qi] = e_i[qi]; }
        sm_acc[accid][qi][d0 + 0] = acc[qi].x;
        sm_acc[accid][qi][d0 + 1] = acc[qi].y;
        sm_acc[accid][qi][d0 + 2] = acc[qi].z;
        sm_acc[accid][qi][d0 + 3] = acc[qi].w;
    }
    __syncthreads();

    const int r = w * SPLIT + p;         // partial id 0..NPART-1
    for (int pi = tid; pi < QPG * HEAD_SIZE; pi += 256) {
        const int qi = pi >> 7;
        const int d  = pi & (HEAD_SIZE - 1);
        float gm = NEG_BIG;
#pragma unroll
        for (int hh = 0; hh < 8; ++hh) gm = fmaxf(gm, sm_m[hh][qi]);
        float num = 0.f, den = 0.f;
#pragma unroll
        for (int hh = 0; hh < 8; ++hh) {
            const float sc = __expf(sm_m[hh][qi] - gm);   // empty half: e=0, acc=0 -> no contrib
            num += sm_acc[hh][qi][d] * sc;
            den += sm_e[hh][qi] * sc;
        }
        const size_t idx = (((size_t)r * S + s) * G + g) * QPG + qi;
        acc_ws[idx * HEAD_SIZE + d] = num;
        if (d == 0) { m_ws[idx] = gm; e_ws[idx] = den; }
    }
}

// Kernel 2: LSE combine over NPART partials. One block per (s,g).
__global__ __launch_bounds__(256)
void pa_reduce_kernel(const float* __restrict__ acc_ws,
                      const float* __restrict__ m_ws,
                      const float* __restrict__ e_ws,
                      float* __restrict__ out)
{
    const int bx = blockIdx.x;       // s*G + g
    const int s = bx / G, g = bx % G;
    const int tid = threadIdx.x;
    for (int pi = tid; pi < QPG * HEAD_SIZE; pi += 256) {
        const int qi = pi >> 7;
        const int d  = pi & (HEAD_SIZE - 1);
        float mw[NPART], ew[NPART];
        float gm = NEG_BIG;
#pragma unroll
        for (int r = 0; r < NPART; ++r) {
            const size_t idx = (((size_t)r * S + s) * G + g) * QPG + qi;
            mw[r] = m_ws[idx];
            ew[r] = e_ws[idx];
            gm = fmaxf(gm, mw[r]);
        }
        float num = 0.f, den = 0.f;
#pragma unroll
        for (int r = 0; r < NPART; ++r) {
            const float sc = __expf(mw[r] - gm);
            const size_t idx = (((size_t)r * S + s) * G + g) * QPG + qi;
            num += acc_ws[idx * HEAD_SIZE + d] * sc;
            den += ew[r] * sc;
        }
        out[((size_t)s * NUM_HEADS + g * QPG + qi) * HEAD_SIZE + d] = num / den;
    }
}

// Fallback fused single-kernel path (no workspace): the round-1 kernel,
// kept for safety if ws_size is ever too small. One block per (s,g).
__global__ __launch_bounds__(256)
void pa_fused_kernel(const float* __restrict__ query,
                     const float* __restrict__ key_cache,
                     const float* __restrict__ value_cache,
                     const int* __restrict__ block_tables,
                     const int* __restrict__ context_lens,
                     float* __restrict__ out)
{
    const int bx = blockIdx.x;
    const int s = bx / G, g = bx % G;
    const int tid   = threadIdx.x;
    const int accid = tid >> 5;
    const int lane  = tid & 31;
    const int d0    = lane * 4;

    __shared__ int   bt_lds[MAX_BLOCKS];
    __shared__ float sm_m[8][QPG];
    __shared__ float sm_e[8][QPG];
    __shared__ float sm_acc[8][QPG][HEAD_SIZE];

    float4 qf[QPG];
#pragma unroll
    for (int qi = 0; qi < QPG; ++qi)
        qf[qi] = *reinterpret_cast<const float4*>(
            query + ((size_t)s * NUM_HEADS + g * QPG + qi) * HEAD_SIZE + d0);

    float  m_i[QPG], e_i[QPG];
    float4 acc[QPG];
#pragma unroll
    for (int qi = 0; qi < QPG; ++qi) {
        m_i[qi] = NEG_BIG; e_i[qi] = 0.f;
        acc[qi] = make_float4(0.f, 0.f, 0.f, 0.f);
    }

    for (int w = 0; w < W; ++w) {
        __syncthreads();
        if (tid < MAX_BLOCKS)
            bt_lds[tid] = block_tables[((size_t)w * S + s) * MAX_BLOCKS + tid];
        __syncthreads();
        const int ctx = context_lens[w * S + s];
        const float* kbase = key_cache   + (size_t)w * WG_STRIDE + (size_t)g * BLOCK_SZ * HEAD_SIZE;
        const float* vbase = value_cache + (size_t)w * WG_STRIDE + (size_t)g * BLOCK_SZ * HEAD_SIZE;
        for (int t = accid; t < ctx; t += 8) {
            const int off = bt_lds[t >> 4] * BLK_STRIDE + (t & 15) * HEAD_SIZE + d0;
            const float4 kx = *reinterpret_cast<const float4*>(kbase + off);
            const float4 vx = *reinterpret_cast<const float4*>(vbase + off);
            float4 dv;
            dv.x = qf[0].x*kx.x + qf[0].y*kx.y + qf[0].z*kx.z + qf[0].w*kx.w;
            dv.y = qf[1].x*kx.x + qf[1].y*kx.y + qf[1].z*kx.z + qf[1].w*kx.w;
            dv.z = qf[2].x*kx.x + qf[2].y*kx.y + qf[2].z*kx.z + qf[2].w*kx.w;
            dv.w = qf[3].x*kx.x + qf[3].y*kx.y + qf[3].z*kx.z + qf[3].w*kx.w;
#pragma unroll
            for (int o = 16; o > 0; o >>= 1) {
                dv.x += __shfl_xor(dv.x, o); dv.y += __shfl_xor(dv.y, o);
                dv.z += __shfl_xor(dv.z, o); dv.w += __shfl_xor(dv.w, o);
            }
            const float lg[QPG] = {dv.x*SCALE, dv.y*SCALE, dv.z*SCALE, dv.w*SCALE};
#pragma unroll
            for (int qi = 0; qi < QPG; ++qi) {
                const float mn    = fmaxf(m_i[qi], lg[qi]);
                const float alpha = __expf(m_i[qi] - mn);
                const float pp    = __expf(lg[qi] - mn);
                m_i[qi] = mn;
                e_i[qi] = e_i[qi] * alpha + pp;
                acc[qi].x = fmaf(acc[qi].x, alpha, pp * vx.x);
                acc[qi].y = fmaf(acc[qi].y, alpha, pp * vx.y);
                acc[qi].z = fmaf(acc[qi].z, alpha, pp * vx.z);
                acc[qi].w = fmaf(acc[qi].w, alpha, pp * vx.w);
            }
        }
    }

#pragma unroll
    for (int qi = 0; qi < QPG; ++qi) {
        if (lane == 0) { sm_m[accid][qi] = m_i[qi]; sm_e[accid][qi] = e_i[qi]; }
        sm_acc[accid][qi][d0 + 0] = acc[qi].x;
        sm_acc[accid][qi][d0 + 1] = acc[qi].y;
        sm_acc[accid][qi][d0 + 2] = acc[qi].z;
        sm_acc[accid][qi][d0 + 3] = acc[qi].w;
    }
    __syncthreads();

    for (int pi = tid; pi < QPG * HEAD_SIZE; pi += 256) {
        const int qi = pi >> 7;
        const int d  = pi & (HEAD_SIZE - 1);
        float gm = NEG_BIG;
#pragma unroll
        for (int hh = 0; hh < 8; ++hh) gm = fmaxf(gm, sm_m[hh][qi]);
        float num = 0.f, den = 0.f;
#pragma unroll
        for (int hh = 0; hh < 8; ++hh) {
            const float sc = __expf(sm_m[hh][qi] - gm);
            num += sm_acc[hh][qi][d] * sc;
            den += sm_e[hh][qi] * sc;
        }
        out[((size_t)s * NUM_HEADS + g * QPG + qi) * HEAD_SIZE + d] = num / den;
    }
}

extern "C" void kernel_launch(void* const* d_in, const int* in_sizes, int n_in,
                              void* d_out, int out_size, void* d_ws, size_t ws_size,
                              hipStream_t stream) {
    const float* query        = (const float*)d_in[0];
    const float* key_cache    = (const float*)d_in[1];
    const float* value_cache  = (const float*)d_in[2];
    const int*   block_tables = (const int*)d_in[3];
    const int*   context_lens = (const int*)d_in[4];
    float* out = (float*)d_out;

    const size_t n_acc   = (size_t)NPART * S * G * QPG * HEAD_SIZE;
    const size_t n_stats = (size_t)NPART * S * G * QPG;
    const size_t need    = (n_acc + 2 * n_stats) * sizeof(float);

    if (ws_size >= need) {
        float* acc_ws = (float*)d_ws;
        float* m_ws   = acc_ws + n_acc;
        float* e_ws   = m_ws + n_stats;
        pa_partial_kernel<<<W * S * G * SPLIT, 256, 0, stream>>>(
            query, key_cache, value_cache, block_tables, context_lens,
            acc_ws, m_ws, e_ws);
        pa_reduce_kernel<<<S * G, 256, 0, stream>>>(acc_ws, m_ws, e_ws, out);
    } else {
        pa_fused_kernel<<<S * G, 256, 0, stream>>>(
            query, key_cache, value_cache, block_tables, context_lens, out);
    }
}